// Round 2
// baseline (1746.292 us; speedup 1.0000x reference)
//
#include <hip/hip_runtime.h>
#include <hip/hip_bf16.h>

#define D_IN 32
#define D_MODEL 128
#define BATCH 512
#define TT 512
#define GB 16   // batch rows per block

typedef __attribute__((ext_vector_type(8))) short bf16x8;
typedef __attribute__((ext_vector_type(4))) float f32x4;

__device__ inline short bf16_of(float f) {
    union { float f; unsigned u; } v; v.f = f;
    unsigned r = v.u + 0x7FFFu + ((v.u >> 16) & 1u);
    return (short)(r >> 16);
}

__device__ inline bf16x8 load8_bf16(const float* __restrict__ p) {
    bf16x8 r;
#pragma unroll
    for (int e = 0; e < 8; ++e) r[e] = bf16_of(p[e]);
    return r;
}

__device__ inline float sigmoidf_fast(float x) {
    return 1.0f / (1.0f + __expf(-x));
}
__device__ inline float tanhf_fast(float x) {
    return 1.0f - 2.0f / (__expf(2.0f * x) + 1.0f);
}

// barrier that waits ONLY on LDS ops — leaves global loads/stores in flight
// (a plain __syncthreads() emits s_waitcnt vmcnt(0) and drains our prefetch)
__device__ inline void lds_barrier() {
    asm volatile("s_waitcnt lgkmcnt(0)\n\ts_barrier" ::: "memory");
}

__launch_bounds__(512, 1)
__global__ void rnn_imputer(const float* __restrict__ x,
                            const float* __restrict__ W_ih,
                            const float* __restrict__ W_hh,
                            const float* __restrict__ b_ih,
                            const float* __restrict__ b_hh,
                            const float* __restrict__ W_out,
                            const float* __restrict__ b_out,
                            const int*   __restrict__ mask,
                            float* __restrict__ out) {
    // LDS: staged x_t (bf16) and double-buffered h (bf16, A-frag layout)
    __shared__ __align__(16) short xt[GB][72];        // [0,32)=x_p, [32,64)=mask, pad->72 (144B rows)
    __shared__ __align__(16) short hbuf[2][GB][136];  // h bf16, 272B rows

    const int tid  = threadIdx.x;
    const int wv   = tid >> 6;       // wave 0..7
    const int lane = tid & 63;
    const int q    = lane >> 4;      // quad 0..3
    const int c    = lane & 15;
    const int bb   = blockIdx.x * GB;
    const int i_col = wv * 16 + c;   // this lane's gate/hidden column (0..127)

    // ---- B fragments (weights, bf16), stationary in registers ----
    // wave wv owns gate-cols [wv*16, wv*16+16) for each of r,z,xn,hn
    bf16x8 Br[6], Bz[6], Bxn[2], Bhn[4], Bo[4];
#pragma unroll
    for (int kt = 0; kt < 6; ++kt) {
        const int k = kt * 32 + q * 8;     // fused K: [0,64)=W_ih, [64,192)=W_hh
        const float* sr = (k < 64) ? (W_ih + (size_t)i_col * 64 + k)
                                   : (W_hh + (size_t)i_col * 128 + (k - 64));
        Br[kt] = load8_bf16(sr);
        const float* sz = (k < 64) ? (W_ih + (size_t)(128 + i_col) * 64 + k)
                                   : (W_hh + (size_t)(128 + i_col) * 128 + (k - 64));
        Bz[kt] = load8_bf16(sz);
    }
#pragma unroll
    for (int kt = 0; kt < 2; ++kt)
        Bxn[kt] = load8_bf16(W_ih + (size_t)(256 + i_col) * 64 + kt * 32 + q * 8);
#pragma unroll
    for (int kt = 0; kt < 4; ++kt)
        Bhn[kt] = load8_bf16(W_hh + (size_t)(256 + i_col) * 128 + kt * 32 + q * 8);

    float bo = 0.0f;
    if (wv < 2) {  // readout cols 0..31
#pragma unroll
        for (int kt = 0; kt < 4; ++kt)
            Bo[kt] = load8_bf16(W_out + (size_t)i_col * 128 + kt * 32 + q * 8);
        bo = b_out[i_col];
    }

    const float bR  = b_ih[i_col]       + b_hh[i_col];
    const float bZ  = b_ih[128 + i_col] + b_hh[128 + i_col];
    const float bXN = b_ih[256 + i_col];
    const float bHN = b_hh[256 + i_col];

    float h_reg[4] = {0.f, 0.f, 0.f, 0.f};   // fp32 h[m=q*4+r][i_col]

    // ---- init: out[:,0]=b_out, stage x_0, zero hbuf[0] ----
    {
        const int b = tid >> 5, ii = tid & 31;
        const size_t o = ((size_t)(bb + b) * TT) * D_IN + ii;
        const float xv = x[o];
        const int   mk = mask[o];
        const float x0 = b_out[ii];
        out[o] = x0;
        xt[b][ii]      = bf16_of(mk ? xv : x0);
        xt[b][32 + ii] = mk ? (short)0x3F80 : (short)0;
    }
    for (int e = tid; e < GB * 128; e += 512)
        hbuf[0][e >> 7][e & 127] = (short)0;

    // ---- prefetch x/mask for t=1 (buf 1) and t=2 (buf 0), waves 0-1 ----
    float pfx[2][4]; int pfm[2][4];
    if (wv < 2) {
#pragma unroll
        for (int r = 0; r < 4; ++r) {
            const int m = q * 4 + r;
            const size_t o1 = ((size_t)(bb + m) * TT + 1) * D_IN + i_col;
            const size_t o2 = ((size_t)(bb + m) * TT + 2) * D_IN + i_col;
            pfx[1][r] = x[o1]; pfm[1][r] = mask[o1];
            pfx[0][r] = x[o2]; pfm[0][r] = mask[o2];
        }
    }
    __syncthreads();   // full barrier once (init)

    for (int t = 0; t < TT - 1; ++t) {
        const int cur = t & 1, nxt = cur ^ 1;

        // ---- phase B: gate GEMMs + in-register GRU update ----
        bf16x8 A[6];
        A[0] = *(const bf16x8*)&xt[c][q * 8];
        A[1] = *(const bf16x8*)&xt[c][32 + q * 8];
#pragma unroll
        for (int kt = 0; kt < 4; ++kt)
            A[2 + kt] = *(const bf16x8*)&hbuf[cur][c][kt * 32 + q * 8];

        f32x4 aR  = (f32x4){0.f, 0.f, 0.f, 0.f};
        f32x4 aZ  = (f32x4){0.f, 0.f, 0.f, 0.f};
        f32x4 aXN = (f32x4){0.f, 0.f, 0.f, 0.f};
        f32x4 aHN = (f32x4){0.f, 0.f, 0.f, 0.f};
#pragma unroll
        for (int kt = 0; kt < 6; ++kt) {
            aR = __builtin_amdgcn_mfma_f32_16x16x32_bf16(A[kt], Br[kt], aR, 0, 0, 0);
            aZ = __builtin_amdgcn_mfma_f32_16x16x32_bf16(A[kt], Bz[kt], aZ, 0, 0, 0);
        }
#pragma unroll
        for (int kt = 0; kt < 2; ++kt)
            aXN = __builtin_amdgcn_mfma_f32_16x16x32_bf16(A[kt], Bxn[kt], aXN, 0, 0, 0);
#pragma unroll
        for (int kt = 0; kt < 4; ++kt)
            aHN = __builtin_amdgcn_mfma_f32_16x16x32_bf16(A[2 + kt], Bhn[kt], aHN, 0, 0, 0);

        // GRU elementwise entirely in-register (C layout: row m=q*4+r, col=i_col)
#pragma unroll
        for (int r = 0; r < 4; ++r) {
            const float rr = sigmoidf_fast(aR[r] + bR);
            const float zz = sigmoidf_fast(aZ[r] + bZ);
            const float nn = tanhf_fast(aXN[r] + bXN + rr * (aHN[r] + bHN));
            const float h  = (1.0f - zz) * nn + zz * h_reg[r];
            h_reg[r] = h;
            hbuf[nxt][q * 4 + r][i_col] = bf16_of(h);
        }
        lds_barrier();   // h_new visible to all waves

        // ---- readout + staging of x_{t+1} (waves 0-1 only) ----
        if (wv < 2) {
            bf16x8 Ah[4];
#pragma unroll
            for (int kt = 0; kt < 4; ++kt)
                Ah[kt] = *(const bf16x8*)&hbuf[nxt][c][kt * 32 + q * 8];
            f32x4 ao = (f32x4){0.f, 0.f, 0.f, 0.f};
#pragma unroll
            for (int kt = 0; kt < 4; ++kt)
                ao = __builtin_amdgcn_mfma_f32_16x16x32_bf16(Ah[kt], Bo[kt], ao, 0, 0, 0);

            const int p = (t + 1) & 1;
            const int tpre = (t + 3 <= TT - 1) ? (t + 3) : (TT - 1);
#pragma unroll
            for (int r = 0; r < 4; ++r) {
                const int m = q * 4 + r;
                const float xh = ao[r] + bo;
                out[((size_t)(bb + m) * TT + (t + 1)) * D_IN + i_col] = xh;
                const float xp = pfm[p][r] ? pfx[p][r] : xh;
                xt[m][i_col]      = bf16_of(xp);
                xt[m][32 + i_col] = pfm[p][r] ? (short)0x3F80 : (short)0;
                // refill this buffer for step t+2 (uses t+3)
                const size_t op = ((size_t)(bb + m) * TT + tpre) * D_IN + i_col;
                pfx[p][r] = x[op]; pfm[p][r] = mask[op];
            }
        }
        lds_barrier();   // staged x_{t+1} visible before next gate phase
    }
}

extern "C" void kernel_launch(void* const* d_in, const int* in_sizes, int n_in,
                              void* d_out, int out_size, void* d_ws, size_t ws_size,
                              hipStream_t stream) {
    const float* x     = (const float*)d_in[0];
    const float* W_ih  = (const float*)d_in[1];
    const float* W_hh  = (const float*)d_in[2];
    const float* b_ih  = (const float*)d_in[3];
    const float* b_hh  = (const float*)d_in[4];
    const float* W_out = (const float*)d_in[5];
    const float* b_out = (const float*)d_in[6];
    const int*   mask  = (const int*)d_in[7];
    float* out = (float*)d_out;

    rnn_imputer<<<dim3(BATCH / GB), dim3(512), 0, stream>>>(
        x, W_ih, W_hh, b_ih, b_hh, W_out, b_out, mask, out);
}

// Round 3
// 1140.652 us; speedup vs baseline: 1.5310x; 1.5310x over previous
//
#include <hip/hip_runtime.h>
#include <hip/hip_bf16.h>

#define D_IN 32
#define TT 512
#define GB 16   // batch rows per block
#define NBLK 32

typedef __attribute__((ext_vector_type(8))) short bf16x8;
typedef __attribute__((ext_vector_type(4))) float f32x4;
typedef __attribute__((ext_vector_type(4))) int   i32x4;
typedef __attribute__((ext_vector_type(2))) unsigned u32x2;

__device__ inline short bf16_of(float f) {
    union { float f; unsigned u; } v; v.f = f;
    unsigned r = v.u + 0x7FFFu + ((v.u >> 16) & 1u);
    return (short)(r >> 16);
}

__device__ inline unsigned pack2(float a, float b) {
    return ((unsigned)(unsigned short)bf16_of(a)) |
           (((unsigned)(unsigned short)bf16_of(b)) << 16);
}

__device__ inline bf16x8 load8_bf16(const float* __restrict__ p) {
    bf16x8 r;
#pragma unroll
    for (int e = 0; e < 8; ++e) r[e] = bf16_of(p[e]);
    return r;
}

// fast sigmoid/tanh: v_exp + v_rcp (1-ulp approx; bf16 noise dominates)
__device__ inline float sigmoid_fast(float x) {
    return __builtin_amdgcn_rcpf(1.0f + __expf(-x));
}
__device__ inline float tanh_fast(float x) {
    return 1.0f - 2.0f * __builtin_amdgcn_rcpf(__expf(2.0f * x) + 1.0f);
}

// barrier waiting only on LDS (keeps global prefetch loads/stores in flight)
__device__ inline void lds_barrier() {
    asm volatile("s_waitcnt lgkmcnt(0)\n\ts_barrier" ::: "memory");
}

__launch_bounds__(512, 1)
__global__ void rnn_imputer(const float* __restrict__ x,
                            const float* __restrict__ W_ih,
                            const float* __restrict__ W_hh,
                            const float* __restrict__ b_ih,
                            const float* __restrict__ b_hh,
                            const float* __restrict__ W_out,
                            const float* __restrict__ b_out,
                            const int*   __restrict__ mask,
                            float* __restrict__ out) {
    // per-wave private x_t slice: [0,32)=x_p bf16, [32,64)=mask bf16, pad->72
    __shared__ __align__(16) short xt_w[8][GB][72];
    // shared h (bf16, A/B-frag row-major), double-buffered; one barrier/step
    __shared__ __align__(16) short hbuf[2][GB][136];

    const int tid  = threadIdx.x;
    const int wv   = tid >> 6;       // wave 0..7
    const int lane = tid & 63;
    const int q    = lane >> 4;      // quad 0..3
    const int c    = lane & 15;
    const int bb   = blockIdx.x * GB;
    const int i_col = wv * 16 + c;   // this wave's gate/hidden column

    // ---- stationary weight B-fragments (bf16) ----
    bf16x8 Br[6], Bz[6], Bxn[2], Bhn[4];
#pragma unroll
    for (int kt = 0; kt < 6; ++kt) {
        const int k = kt * 32 + q * 8;     // fused K: [0,64)=W_ih, [64,192)=W_hh
        const float* sr = (k < 64) ? (W_ih + (size_t)i_col * 64 + k)
                                   : (W_hh + (size_t)i_col * 128 + (k - 64));
        Br[kt] = load8_bf16(sr);
        const float* sz = (k < 64) ? (W_ih + (size_t)(128 + i_col) * 64 + k)
                                   : (W_hh + (size_t)(128 + i_col) * 128 + (k - 64));
        Bz[kt] = load8_bf16(sz);
    }
#pragma unroll
    for (int kt = 0; kt < 2; ++kt)
        Bxn[kt] = load8_bf16(W_ih + (size_t)(256 + i_col) * 64 + kt * 32 + q * 8);
#pragma unroll
    for (int kt = 0; kt < 4; ++kt)
        Bhn[kt] = load8_bf16(W_hh + (size_t)(256 + i_col) * 128 + kt * 32 + q * 8);

    // readout A-fragments: W_out rows = out-cols (all waves, redundant)
    bf16x8 Ao[2][4];
#pragma unroll
    for (int ta = 0; ta < 2; ++ta)
#pragma unroll
        for (int kt = 0; kt < 4; ++kt)
            Ao[ta][kt] = load8_bf16(W_out + (size_t)(ta * 16 + c) * 128 + kt * 32 + q * 8);

    f32x4 bo_v[2];
#pragma unroll
    for (int ta = 0; ta < 2; ++ta)
        bo_v[ta] = *(const f32x4*)&b_out[ta * 16 + q * 4];

    const float bR  = b_ih[i_col]       + b_hh[i_col];
    const float bZ  = b_ih[128 + i_col] + b_hh[128 + i_col];
    const float bXN = b_ih[256 + i_col];
    const float bHN = b_hh[256 + i_col];

    float h_reg[4] = {0.f, 0.f, 0.f, 0.f};

    // ---- init: out[:,0]=b_out; stage x_0 into own slice ----
    {
        const size_t rb = (size_t)(bb + c) * TT * D_IN;   // t = 0 row base, batch c
#pragma unroll
        for (int ta = 0; ta < 2; ++ta) {
            const f32x4 xv = *(const f32x4*)&x[rb + ta * 16 + q * 4];
            const i32x4 mv = *(const i32x4*)&mask[rb + ta * 16 + q * 4];
            float v0 = mv[0] ? xv[0] : bo_v[ta][0];
            float v1 = mv[1] ? xv[1] : bo_v[ta][1];
            float v2 = mv[2] ? xv[2] : bo_v[ta][2];
            float v3 = mv[3] ? xv[3] : bo_v[ta][3];
            u32x2 px, pm;
            px[0] = pack2(v0, v1); px[1] = pack2(v2, v3);
            pm[0] = (mv[0] ? 0x3F80u : 0u) | ((mv[1] ? 0x3F80u : 0u) << 16);
            pm[1] = (mv[2] ? 0x3F80u : 0u) | ((mv[3] ? 0x3F80u : 0u) << 16);
            *(u32x2*)&xt_w[wv][c][ta * 16 + q * 4]      = px;
            *(u32x2*)&xt_w[wv][c][32 + ta * 16 + q * 4] = pm;
            if (wv == ta)
                *(f32x4*)&out[rb + ta * 16 + q * 4] = bo_v[ta];
        }
    }
    // initial A-frags (same-wave LDS round trip, no barrier)
    bf16x8 A0 = *(const bf16x8*)&xt_w[wv][c][q * 8];
    bf16x8 A1 = *(const bf16x8*)&xt_w[wv][c][32 + q * 8];

    // prefetch x/mask for t=1 (parity 1) and t=2 (parity 0)
    f32x4 pfx[2][2]; i32x4 pfm[2][2];
#pragma unroll
    for (int par = 0; par < 2; ++par) {
        const int tt = par ? 1 : 2;
#pragma unroll
        for (int ta = 0; ta < 2; ++ta) {
            const size_t o = ((size_t)(bb + c) * TT + tt) * D_IN + ta * 16 + q * 4;
            pfx[par][ta] = *(const f32x4*)&x[o];
            pfm[par][ta] = *(const i32x4*)&mask[o];
        }
    }

    // gate accumulators (h-part pre-accumulated each iter; h_0=0 -> start 0)
    f32x4 accR  = (f32x4){0.f, 0.f, 0.f, 0.f};
    f32x4 accZ  = (f32x4){0.f, 0.f, 0.f, 0.f};
    f32x4 accXN = (f32x4){0.f, 0.f, 0.f, 0.f};
    f32x4 accHN = (f32x4){0.f, 0.f, 0.f, 0.f};

    for (int t = 0; t < TT - 1; ++t) {
        // ---- x-part gate MFMAs (6) ----
        accR  = __builtin_amdgcn_mfma_f32_16x16x32_bf16(A0, Br[0],  accR,  0, 0, 0);
        accZ  = __builtin_amdgcn_mfma_f32_16x16x32_bf16(A0, Bz[0],  accZ,  0, 0, 0);
        accXN = __builtin_amdgcn_mfma_f32_16x16x32_bf16(A0, Bxn[0], accXN, 0, 0, 0);
        accR  = __builtin_amdgcn_mfma_f32_16x16x32_bf16(A1, Br[1],  accR,  0, 0, 0);
        accZ  = __builtin_amdgcn_mfma_f32_16x16x32_bf16(A1, Bz[1],  accZ,  0, 0, 0);
        accXN = __builtin_amdgcn_mfma_f32_16x16x32_bf16(A1, Bxn[1], accXN, 0, 0, 0);

        // ---- GRU elementwise in-register; write h_{t+1} bf16 to hbuf ----
        const int pb = (t + 1) & 1;
#pragma unroll
        for (int r = 0; r < 4; ++r) {
            const float rr = sigmoid_fast(accR[r] + bR);
            const float zz = sigmoid_fast(accZ[r] + bZ);
            const float nn = tanh_fast(accXN[r] + bXN + rr * (accHN[r] + bHN));
            const float h  = nn + zz * (h_reg[r] - nn);
            h_reg[r] = h;
            hbuf[pb][q * 4 + r][i_col] = bf16_of(h);
        }
        lds_barrier();   // the ONLY barrier per step

        // ---- read h_{t+1} frags (B for readout == A for next gates) ----
        bf16x8 Ah[4];
#pragma unroll
        for (int kt = 0; kt < 4; ++kt)
            Ah[kt] = *(const bf16x8*)&hbuf[pb][c][kt * 32 + q * 8];

        // ---- redundant readout (8 MFMAs) + pre-issue h-part gates (12) ----
        f32x4 aO0 = (f32x4){0.f, 0.f, 0.f, 0.f};
        f32x4 aO1 = (f32x4){0.f, 0.f, 0.f, 0.f};
        accR  = (f32x4){0.f, 0.f, 0.f, 0.f};
        accZ  = (f32x4){0.f, 0.f, 0.f, 0.f};
        accXN = (f32x4){0.f, 0.f, 0.f, 0.f};
        accHN = (f32x4){0.f, 0.f, 0.f, 0.f};
#pragma unroll
        for (int kt = 0; kt < 4; ++kt) {
            aO0  = __builtin_amdgcn_mfma_f32_16x16x32_bf16(Ao[0][kt], Ah[kt], aO0, 0, 0, 0);
            aO1  = __builtin_amdgcn_mfma_f32_16x16x32_bf16(Ao[1][kt], Ah[kt], aO1, 0, 0, 0);
            accR = __builtin_amdgcn_mfma_f32_16x16x32_bf16(Ah[kt], Br[2 + kt], accR, 0, 0, 0);
            accZ = __builtin_amdgcn_mfma_f32_16x16x32_bf16(Ah[kt], Bz[2 + kt], accZ, 0, 0, 0);
            accHN = __builtin_amdgcn_mfma_f32_16x16x32_bf16(Ah[kt], Bhn[kt], accHN, 0, 0, 0);
        }

        // ---- x_hat, out store (split across waves 0/1), stage x_{t+1} ----
        const int p  = (t + 1) & 1;
        int tp = t + 3; if (tp > TT - 1) tp = TT - 1;
#pragma unroll
        for (int ta = 0; ta < 2; ++ta) {
            const f32x4 aO = ta ? aO1 : aO0;
            f32x4 xh;
#pragma unroll
            for (int r = 0; r < 4; ++r) xh[r] = aO[r] + bo_v[ta][r];
            if (wv == ta)
                *(f32x4*)&out[((size_t)(bb + c) * TT + (t + 1)) * D_IN + ta * 16 + q * 4] = xh;
            float v0 = pfm[p][ta][0] ? pfx[p][ta][0] : xh[0];
            float v1 = pfm[p][ta][1] ? pfx[p][ta][1] : xh[1];
            float v2 = pfm[p][ta][2] ? pfx[p][ta][2] : xh[2];
            float v3 = pfm[p][ta][3] ? pfx[p][ta][3] : xh[3];
            u32x2 px, pm;
            px[0] = pack2(v0, v1); px[1] = pack2(v2, v3);
            pm[0] = (pfm[p][ta][0] ? 0x3F80u : 0u) | ((pfm[p][ta][1] ? 0x3F80u : 0u) << 16);
            pm[1] = (pfm[p][ta][2] ? 0x3F80u : 0u) | ((pfm[p][ta][3] ? 0x3F80u : 0u) << 16);
            *(u32x2*)&xt_w[wv][c][ta * 16 + q * 4]      = px;
            *(u32x2*)&xt_w[wv][c][32 + ta * 16 + q * 4] = pm;
            // refill prefetch for step t+2 (uses time t+3)
            const size_t o = ((size_t)(bb + c) * TT + tp) * D_IN + ta * 16 + q * 4;
            pfx[p][ta] = *(const f32x4*)&x[o];
            pfm[p][ta] = *(const i32x4*)&mask[o];
        }
        // re-read next-step A-frags from own slice (same wave, in-order DS)
        A0 = *(const bf16x8*)&xt_w[wv][c][q * 8];
        A1 = *(const bf16x8*)&xt_w[wv][c][32 + q * 8];
    }
}

extern "C" void kernel_launch(void* const* d_in, const int* in_sizes, int n_in,
                              void* d_out, int out_size, void* d_ws, size_t ws_size,
                              hipStream_t stream) {
    const float* x     = (const float*)d_in[0];
    const float* W_ih  = (const float*)d_in[1];
    const float* W_hh  = (const float*)d_in[2];
    const float* b_ih  = (const float*)d_in[3];
    const float* b_hh  = (const float*)d_in[4];
    const float* W_out = (const float*)d_in[5];
    const float* b_out = (const float*)d_in[6];
    const int*   mask  = (const int*)d_in[7];
    float* out = (float*)d_out;

    rnn_imputer<<<dim3(NBLK), dim3(512), 0, stream>>>(
        x, W_ih, W_hh, b_ih, b_hh, W_out, b_out, mask, out);
}